// Round 1
// baseline (1813.292 us; speedup 1.0000x reference)
//
#include <hip/hip_runtime.h>
#include <cstdint>
#include <cstddef>

// Problem constants
#define D_    512
#define H_    4
#define DH_   128
#define FFN_  128
#define L_    4
#define B_    8
#define T_    1025
#define U_    1024
#define NSEG_ 256
#define R_    256
#define TOT_  1280            // R + U
#define M_    (B_*TOT_)       // 10240 rows

// ---------------------------------------------------------------------------
// gather: build cat = [r, u] from x.  r[s] = x[:, rc_idx[s]], rc_idx[s] =
// 4*(s+1) for s<255, 1024 for s=255.  u[j] = x[:, j].
// ---------------------------------------------------------------------------
__global__ __launch_bounds__(256)
void gather_k(const float* __restrict__ x, float* __restrict__ X) {
  size_t i = (size_t)blockIdx.x * 256 + threadIdx.x;
  if (i >= (size_t)M_ * D_) return;
  int c = (int)(i & (D_ - 1));
  size_t row = i >> 9;                 // D_ == 512
  int b = (int)(row / TOT_), p = (int)(row % TOT_);
  int t = (p < R_) ? ((p < R_ - 1) ? 4 * (p + 1) : (T_ - 1)) : (p - R_);
  X[i] = x[((size_t)b * T_ + t) * D_ + c];
}

// ---------------------------------------------------------------------------
// LayerNorm over D=512. One block (256 thr) per row; 2 elems per thread.
// Works in-place (each element read+written by owning thread only).
// ---------------------------------------------------------------------------
__global__ __launch_bounds__(256)
void ln_k(const float* __restrict__ X, const float* __restrict__ g,
          const float* __restrict__ bb, float* __restrict__ Y) {
  int row = blockIdx.x;
  int tid = threadIdx.x;
  const float* xr = X + (size_t)row * D_;
  float e0 = xr[tid], e1 = xr[tid + 256];
  float s = e0 + e1, ss = e0 * e0 + e1 * e1;
#pragma unroll
  for (int off = 32; off > 0; off >>= 1) {
    s  += __shfl_down(s, off);
    ss += __shfl_down(ss, off);
  }
  __shared__ float red[10];
  int wid = tid >> 6, lane = tid & 63;
  if (lane == 0) { red[wid] = s; red[4 + wid] = ss; }
  __syncthreads();
  if (tid == 0) {
    float S = red[0] + red[1] + red[2] + red[3];
    float SS = red[4] + red[5] + red[6] + red[7];
    float mu = S * (1.0f / D_);
    float var = SS * (1.0f / D_) - mu * mu;
    if (var < 0.f) var = 0.f;
    red[8] = mu;
    red[9] = rsqrtf(var + 1e-5f);
  }
  __syncthreads();
  float mu = red[8], rs = red[9];
  float* yr = Y + (size_t)row * D_;
  yr[tid]       = (e0 - mu) * rs * g[tid]       + bb[tid];
  yr[tid + 256] = (e1 - mu) * rs * g[tid + 256] + bb[tid + 256];
}

// ---------------------------------------------------------------------------
// fp32 GEMM:  C[M,N] = A[M,K] @ B[N,K]^T + bias[N]  (+ residual) (+ relu)
// 64x64 tile, BK=16, 256 threads, 4x4 microtile per thread.
// ---------------------------------------------------------------------------
#define BM 64
#define BN 64
#define BK 16
#define LDP 68   // padded LDS leading dim: k*68*4 bytes keeps float4 alignment

template <bool RELU, bool RESID>
__global__ __launch_bounds__(256)
void gemm_bt(const float* __restrict__ A, const float* __restrict__ B,
             const float* __restrict__ bias, const float* __restrict__ Rsd,
             float* __restrict__ C, int M, int N, int K) {
  __shared__ float As[BK][LDP];
  __shared__ float Bs[BK][LDP];
  int tid = threadIdx.x;
  int tx = tid & 15;          // n micro index
  int ty = tid >> 4;          // m micro index
  int bm = blockIdx.y * BM;
  int bn = blockIdx.x * BN;
  int lr = tid >> 2;          // 0..63 : row within tile
  int lk = (tid & 3) * 4;     // 0,4,8,12 : k offset
  float acc[4][4] = {};
  const float* Ap = A + (size_t)(bm + lr) * K + lk;
  const float* Bp = B + (size_t)(bn + lr) * K + lk;
  for (int k0 = 0; k0 < K; k0 += BK) {
    float4 av = *(const float4*)(Ap + k0);
    float4 bv = *(const float4*)(Bp + k0);
    __syncthreads();
    As[lk + 0][lr] = av.x; As[lk + 1][lr] = av.y;
    As[lk + 2][lr] = av.z; As[lk + 3][lr] = av.w;
    Bs[lk + 0][lr] = bv.x; Bs[lk + 1][lr] = bv.y;
    Bs[lk + 2][lr] = bv.z; Bs[lk + 3][lr] = bv.w;
    __syncthreads();
#pragma unroll
    for (int k = 0; k < BK; ++k) {
      float4 a = *(const float4*)&As[k][ty * 4];
      float4 b = *(const float4*)&Bs[k][tx * 4];
      acc[0][0] += a.x * b.x; acc[0][1] += a.x * b.y; acc[0][2] += a.x * b.z; acc[0][3] += a.x * b.w;
      acc[1][0] += a.y * b.x; acc[1][1] += a.y * b.y; acc[1][2] += a.y * b.z; acc[1][3] += a.y * b.w;
      acc[2][0] += a.z * b.x; acc[2][1] += a.z * b.y; acc[2][2] += a.z * b.z; acc[2][3] += a.z * b.w;
      acc[3][0] += a.w * b.x; acc[3][1] += a.w * b.y; acc[3][2] += a.w * b.z; acc[3][3] += a.w * b.w;
    }
  }
  float4 b4 = *(const float4*)&bias[bn + tx * 4];
#pragma unroll
  for (int i = 0; i < 4; ++i) {
    int m = bm + ty * 4 + i;
    float4 v;
    v.x = acc[i][0] + b4.x; v.y = acc[i][1] + b4.y;
    v.z = acc[i][2] + b4.z; v.w = acc[i][3] + b4.w;
    if (RESID) {
      float4 r4 = *(const float4*)(Rsd + (size_t)m * N + bn + tx * 4);
      v.x += r4.x; v.y += r4.y; v.z += r4.z; v.w += r4.w;
    }
    if (RELU) {
      v.x = fmaxf(v.x, 0.f); v.y = fmaxf(v.y, 0.f);
      v.z = fmaxf(v.z, 0.f); v.w = fmaxf(v.w, 0.f);
    }
    *(float4*)(C + (size_t)m * N + bn + tx * 4) = v;
  }
}

// ---------------------------------------------------------------------------
// Block-diagonal attention. One block per (b, seg); wave h handles head h.
// Rows of segment s: {s, 256+4s .. 256+4s+3}.
// ---------------------------------------------------------------------------
#define QLD 516   // padded LDS stride
__global__ __launch_bounds__(256)
void attn_k(const float* __restrict__ Q, const float* __restrict__ KV,
            float* __restrict__ O) {
  int bs = blockIdx.x;
  int b = bs >> 8, s = bs & 255;
  __shared__ float Qs[5][QLD];
  __shared__ float Ks[5][QLD];
  __shared__ float Vs[5][QLD];
  __shared__ float P[H_][5][5];
  int tid = threadIdx.x;
  const float scale = 0.08838834764831845f;  // 128^-0.5
  int rows[5];
  rows[0] = s;
#pragma unroll
  for (int i = 1; i < 5; ++i) rows[i] = R_ + 4 * s + (i - 1);
  for (int idx = tid; idx < 5 * D_; idx += 256) {
    int i = idx >> 9, c = idx & (D_ - 1);
    size_t base = (size_t)b * TOT_ + rows[i];
    Qs[i][c] = Q[base * D_ + c] * scale;
    Ks[i][c] = KV[base * (2 * D_) + c];
    Vs[i][c] = KV[base * (2 * D_) + D_ + c];
  }
  __syncthreads();
  int h = tid >> 6, lane = tid & 63;
  if (lane < 25) {
    int i = lane / 5, j = lane % 5;
    float sum = 0.f;
    const float* qp = &Qs[i][h * DH_];
    const float* kp = &Ks[j][h * DH_];
#pragma unroll 8
    for (int d = 0; d < DH_; ++d) sum += qp[d] * kp[d];
    P[h][i][j] = sum;
  }
  __syncthreads();
  if (lane < 5) {
    int i = lane;
    float m = P[h][i][0];
#pragma unroll
    for (int j = 1; j < 5; ++j) m = fmaxf(m, P[h][i][j]);
    float e[5], ssum = 0.f;
#pragma unroll
    for (int j = 0; j < 5; ++j) { e[j] = __expf(P[h][i][j] - m); ssum += e[j]; }
    float inv = 1.0f / ssum;
#pragma unroll
    for (int j = 0; j < 5; ++j) P[h][i][j] = e[j] * inv;
  }
  __syncthreads();
  for (int idx = lane; idx < 5 * DH_; idx += 64) {
    int i = idx >> 7, d = idx & (DH_ - 1);
    float o = 0.f;
#pragma unroll
    for (int j = 0; j < 5; ++j) o += P[h][i][j] * Vs[j][h * DH_ + d];
    O[((size_t)b * TOT_ + rows[i]) * D_ + h * DH_ + d] = o;
  }
}

// ---------------------------------------------------------------------------
// mean over the 1024 u rows -> (B, D), two stages (no atomics).
// ---------------------------------------------------------------------------
__global__ __launch_bounds__(256)
void mean_part_k(const float* __restrict__ X, float* __restrict__ part) {
  int d = blockIdx.x * 256 + threadIdx.x;       // 0..511
  int jc = blockIdx.y;                          // 0..7
  int b = blockIdx.z;                           // 0..7
  float acc = 0.f;
  const float* base = X + ((size_t)b * TOT_ + R_ + jc * 128) * D_ + d;
  for (int j = 0; j < 128; ++j) acc += base[(size_t)j * D_];
  part[((size_t)b * 8 + jc) * D_ + d] = acc;
}

__global__ __launch_bounds__(256)
void mean_final_k(const float* __restrict__ part, float* __restrict__ out) {
  int i = blockIdx.x * 256 + threadIdx.x;       // 0..4095
  int b = i >> 9, d = i & (D_ - 1);
  float acc = 0.f;
#pragma unroll
  for (int c = 0; c < 8; ++c) acc += part[((size_t)b * 8 + c) * D_ + d];
  out[i] = acc * (1.0f / U_);
}

// ---------------------------------------------------------------------------
// Launch. Workspace layout (floats):
//   X    @ 0          : 5,242,880   (cat / rc_out, in-place across layers)
//   LN   @ 5,242,880  : 5,242,880   (LN-in output; reused as ATT)
//   Qb   @ 10,485,760 : 5,242,880   (Q;      reused as LN2)
//   KVb  @ 15,728,640 : 10,485,760  (KV;     reused as FFN hidden H)
//   part @ 26,214,400 : 32,768
// total ≈ 105 MB.
// ---------------------------------------------------------------------------
extern "C" void kernel_launch(void* const* d_in, const int* in_sizes, int n_in,
                              void* d_out, int out_size, void* d_ws, size_t ws_size,
                              hipStream_t stream) {
  const float* x      = (const float*)d_in[0];
  const float* Wq     = (const float*)d_in[1];
  const float* bq     = (const float*)d_in[2];
  const float* Wkv    = (const float*)d_in[3];
  const float* bkv    = (const float*)d_in[4];
  const float* Wo     = (const float*)d_in[5];
  const float* bo     = (const float*)d_in[6];
  const float* W1     = (const float*)d_in[7];
  const float* b1     = (const float*)d_in[8];
  const float* W2     = (const float*)d_in[9];
  const float* b2     = (const float*)d_in[10];
  const float* ln_in_g  = (const float*)d_in[11];
  const float* ln_in_b  = (const float*)d_in[12];
  const float* ff_ln_g  = (const float*)d_in[13];
  const float* ff_ln_b  = (const float*)d_in[14];
  const float* ln_out_g = (const float*)d_in[15];
  const float* ln_out_b = (const float*)d_in[16];
  float* out = (float*)d_out;

  float* ws   = (float*)d_ws;
  float* X    = ws;
  float* LN   = ws + 5242880;    // also ATT
  float* Qb   = ws + 10485760;   // also LN2
  float* KVb  = ws + 15728640;   // also H
  float* part = ws + 26214400;
  float* ATT = LN;
  float* LN2 = Qb;
  float* Hb  = KVb;

  // build cat
  {
    int total = M_ * D_;
    gather_k<<<(total + 255) / 256, 256, 0, stream>>>(x, X);
  }

  for (int l = 0; l < L_; ++l) {
    const float* Wq_l  = Wq  + (size_t)l * D_ * D_;
    const float* bq_l  = bq  + (size_t)l * D_;
    const float* Wkv_l = Wkv + (size_t)l * 2 * D_ * D_;
    const float* bkv_l = bkv + (size_t)l * 2 * D_;
    const float* Wo_l  = Wo  + (size_t)l * D_ * D_;
    const float* bo_l  = bo  + (size_t)l * D_;
    const float* W1_l  = W1  + (size_t)l * FFN_ * D_;
    const float* b1_l  = b1  + (size_t)l * FFN_;
    const float* W2_l  = W2  + (size_t)l * D_ * FFN_;
    const float* b2_l  = b2  + (size_t)l * D_;

    // LN-in: X -> LN
    ln_k<<<M_, 256, 0, stream>>>(X, ln_in_g + l * D_, ln_in_b + l * D_, LN);

    // Q = LN @ Wq^T + bq        (M x 512)
    gemm_bt<false, false><<<dim3(D_ / BN, M_ / BM), 256, 0, stream>>>(
        LN, Wq_l, bq_l, nullptr, Qb, M_, D_, D_);
    // KV = LN @ Wkv^T + bkv     (M x 1024)
    gemm_bt<false, false><<<dim3(2 * D_ / BN, M_ / BM), 256, 0, stream>>>(
        LN, Wkv_l, bkv_l, nullptr, KVb, M_, 2 * D_, D_);

    // attention -> ATT (reuses LN region)
    attn_k<<<B_ * NSEG_, 256, 0, stream>>>(Qb, KVb, ATT);

    // X = ATT @ Wo^T + bo + X
    gemm_bt<false, true><<<dim3(D_ / BN, M_ / BM), 256, 0, stream>>>(
        ATT, Wo_l, bo_l, X, X, M_, D_, D_);

    // LN-ff: X -> LN2
    ln_k<<<M_, 256, 0, stream>>>(X, ff_ln_g + l * D_, ff_ln_b + l * D_, LN2);

    // H = relu(LN2 @ W1^T + b1)   (M x 128)
    gemm_bt<true, false><<<dim3(FFN_ / BN, M_ / BM), 256, 0, stream>>>(
        LN2, W1_l, b1_l, nullptr, Hb, M_, FFN_, D_);

    // X = H @ W2^T + b2 + X
    gemm_bt<false, true><<<dim3(D_ / BN, M_ / BM), 256, 0, stream>>>(
        Hb, W2_l, b2_l, X, X, M_, D_, FFN_);

    // LN-out in place: X -> X
    ln_k<<<M_, 256, 0, stream>>>(X, ln_out_g + l * D_, ln_out_b + l * D_, X);
  }

  // output mean over u rows
  mean_part_k<<<dim3(2, 8, 8), 256, 0, stream>>>(X, part);
  mean_final_k<<<(B_ * D_) / 256, 256, 0, stream>>>(part, out);
}

// Round 2
// 581.767 us; speedup vs baseline: 3.1169x; 3.1169x over previous
//
#include <hip/hip_runtime.h>
#include <cstdint>
#include <cstddef>

// Problem constants
#define D_    512
#define H_    4
#define DH_   128
#define FFN_  128
#define L_    4
#define B_    8
#define T_    1025
#define U_    1024
#define NSEG_ 256
#define R_    256
#define TOT_  1280            // R + U
#define M_    (B_*TOT_)       // 10240 rows

typedef __attribute__((ext_vector_type(8))) short bf16x8;
typedef __attribute__((ext_vector_type(4))) float f32x4;
typedef unsigned short u16;

__device__ __forceinline__ u16 f2bf(float f) {
  unsigned u = __builtin_bit_cast(unsigned, f);
  u += 0x7fff + ((u >> 16) & 1);           // round-to-nearest-even
  return (u16)(u >> 16);
}
__device__ __forceinline__ float bf2f(u16 h) {
  unsigned u = ((unsigned)h) << 16;
  return __builtin_bit_cast(float, u);
}

__device__ __forceinline__ void gload_lds16(const void* g, void* l) {
  __builtin_amdgcn_global_load_lds(
      (const __attribute__((address_space(1))) unsigned*)g,
      (__attribute__((address_space(3))) unsigned*)l, 16, 0, 0);
}

// ---------------------------------------------------------------------------
// gather: build cat = [r, u] from x (fp32 -> fp32 residual stream X).
// ---------------------------------------------------------------------------
__global__ __launch_bounds__(256)
void gather_k(const float* __restrict__ x, float* __restrict__ X) {
  size_t i = (size_t)blockIdx.x * 256 + threadIdx.x;
  if (i >= (size_t)M_ * D_) return;
  int c = (int)(i & (D_ - 1));
  size_t row = i >> 9;                 // D_ == 512
  int b = (int)(row / TOT_), p = (int)(row % TOT_);
  int t = (p < R_) ? ((p < R_ - 1) ? 4 * (p + 1) : (T_ - 1)) : (p - R_);
  X[i] = x[((size_t)b * T_ + t) * D_ + c];
}

// ---------------------------------------------------------------------------
// fp32 -> bf16 convert (weights), n divisible by 4
// ---------------------------------------------------------------------------
__global__ __launch_bounds__(256)
void cvt_k(const float* __restrict__ in, u16* __restrict__ out, int n) {
  int i = (blockIdx.x * 256 + threadIdx.x) * 4;
  if (i >= n) return;
  float4 v = *(const float4*)(in + i);
  ushort4 o;
  o.x = f2bf(v.x); o.y = f2bf(v.y); o.z = f2bf(v.z); o.w = f2bf(v.w);
  *(ushort4*)(out + i) = o;
}

// ---------------------------------------------------------------------------
// LayerNorm over D=512, one block (256 thr) per row. Templated output dtype.
// ---------------------------------------------------------------------------
template <bool OUT_BF16>
__global__ __launch_bounds__(256)
void ln_k(const float* __restrict__ X, const float* __restrict__ g,
          const float* __restrict__ bb, void* __restrict__ Y) {
  int row = blockIdx.x;
  int tid = threadIdx.x;
  const float* xr = X + (size_t)row * D_;
  float e0 = xr[tid], e1 = xr[tid + 256];
  float s = e0 + e1, ss = e0 * e0 + e1 * e1;
#pragma unroll
  for (int off = 32; off > 0; off >>= 1) {
    s  += __shfl_down(s, off);
    ss += __shfl_down(ss, off);
  }
  __shared__ float red[10];
  int wid = tid >> 6, lane = tid & 63;
  if (lane == 0) { red[wid] = s; red[4 + wid] = ss; }
  __syncthreads();
  if (tid == 0) {
    float S = red[0] + red[1] + red[2] + red[3];
    float SS = red[4] + red[5] + red[6] + red[7];
    float mu = S * (1.0f / D_);
    float var = SS * (1.0f / D_) - mu * mu;
    if (var < 0.f) var = 0.f;
    red[8] = mu;
    red[9] = rsqrtf(var + 1e-5f);
  }
  __syncthreads();
  float mu = red[8], rs = red[9];
  float v0 = (e0 - mu) * rs * g[tid]       + bb[tid];
  float v1 = (e1 - mu) * rs * g[tid + 256] + bb[tid + 256];
  if (OUT_BF16) {
    u16* yr = (u16*)Y + (size_t)row * D_;
    yr[tid] = f2bf(v0); yr[tid + 256] = f2bf(v1);
  } else {
    float* yr = (float*)Y + (size_t)row * D_;
    yr[tid] = v0; yr[tid + 256] = v1;
  }
}

// ---------------------------------------------------------------------------
// bf16 MFMA GEMM:  C[M,N] = A[M,K] @ B[N,K]^T + bias[N] (+ residual fp32)
//                  (+ relu), output bf16 or fp32.
// 128x128 tile, BK=32, 256 threads (4 waves, 2x2), 4x4 16x16x32 frags/wave.
// LDS linear row-major [128][32] bf16, filled by global_load_lds width=16.
// ---------------------------------------------------------------------------
#define GBM 128
#define GBN 128
#define GBK 32

template <bool RELU, bool RESID, bool OUT_BF16>
__global__ __launch_bounds__(256)
void gemm_mfma(const u16* __restrict__ A, const u16* __restrict__ Bw,
               const float* __restrict__ bias, const float* __restrict__ Rsd,
               void* __restrict__ Cout, int M, int N, int K) {
  __shared__ __align__(16) u16 As[GBM * GBK];
  __shared__ __align__(16) u16 Bs[GBN * GBK];
  const int tid = threadIdx.x;
  const int wid = tid >> 6;
  const int lane = tid & 63;
  const int bm = blockIdx.y * GBM;
  const int bn = blockIdx.x * GBN;
  const int wr = wid >> 1, wc = wid & 1;   // 64x64 wave sub-tile

  // staging: thread tid covers (row = tid/4, k-offset = (tid%4)*8)
  const int srow = tid >> 2;
  const int skoff = (tid & 3) << 3;

  f32x4 acc[4][4] = {};

  const u16* Ag0 = A  + (size_t)(bm + srow)      * K + skoff;
  const u16* Ag1 = A  + (size_t)(bm + 64 + srow) * K + skoff;
  const u16* Bg0 = Bw + (size_t)(bn + srow)      * K + skoff;
  const u16* Bg1 = Bw + (size_t)(bn + 64 + srow) * K + skoff;
  u16* AsW0 = &As[(size_t)(wid * 16)      * GBK];   // wave-uniform LDS bases
  u16* AsW1 = &As[(size_t)(64 + wid * 16) * GBK];
  u16* BsW0 = &Bs[(size_t)(wid * 16)      * GBK];
  u16* BsW1 = &Bs[(size_t)(64 + wid * 16) * GBK];

  const int lrow = lane & 15;
  const int lko  = (lane >> 4) * 16;   // byte offset of this lane's k-group

  for (int k0 = 0; k0 < K; k0 += GBK) {
    __syncthreads();                       // prior tile fully consumed
    gload_lds16(Ag0 + k0, AsW0);
    gload_lds16(Ag1 + k0, AsW1);
    gload_lds16(Bg0 + k0, BsW0);
    gload_lds16(Bg1 + k0, BsW1);
    __syncthreads();                       // drains vmcnt -> tile ready

    bf16x8 afrag[4], bfrag[4];
#pragma unroll
    for (int m = 0; m < 4; ++m) {
      int row = wr * 64 + m * 16 + lrow;
      afrag[m] = *(const bf16x8*)((const char*)As + row * (GBK * 2) + lko);
    }
#pragma unroll
    for (int n = 0; n < 4; ++n) {
      int col = wc * 64 + n * 16 + lrow;
      bfrag[n] = *(const bf16x8*)((const char*)Bs + col * (GBK * 2) + lko);
    }
#pragma unroll
    for (int m = 0; m < 4; ++m)
#pragma unroll
      for (int n = 0; n < 4; ++n)
        acc[m][n] = __builtin_amdgcn_mfma_f32_16x16x32_bf16(
            afrag[m], bfrag[n], acc[m][n], 0, 0, 0);
  }

  // epilogue: D layout col = lane&15, row = (lane>>4)*4 + j  [m89]
  const int lcol  = lane & 15;
  const int lrow4 = (lane >> 4) * 4;
#pragma unroll
  for (int m = 0; m < 4; ++m) {
    int rowbase = bm + wr * 64 + m * 16 + lrow4;
#pragma unroll
    for (int n = 0; n < 4; ++n) {
      int col = bn + wc * 64 + n * 16 + lcol;
      float bv = bias[col];
#pragma unroll
      for (int j = 0; j < 4; ++j) {
        int row = rowbase + j;
        float v = acc[m][n][j] + bv;
        if (RESID) v += Rsd[(size_t)row * N + col];
        if (RELU)  v = fmaxf(v, 0.f);
        if (OUT_BF16) ((u16*)Cout)[(size_t)row * N + col] = f2bf(v);
        else          ((float*)Cout)[(size_t)row * N + col] = v;
      }
    }
  }
}

// ---------------------------------------------------------------------------
// Block-diagonal attention (bf16 in, bf16 out, fp32 math in LDS).
// One block per (b, seg); wave h = head h. Segment rows: {s, 256+4s..+3}.
// ---------------------------------------------------------------------------
#define QLD 516   // padded LDS stride
__global__ __launch_bounds__(256)
void attn_k(const u16* __restrict__ Q, const u16* __restrict__ KV,
            u16* __restrict__ O) {
  int bs = blockIdx.x;
  int b = bs >> 8, s = bs & 255;
  __shared__ float Qs[5][QLD];
  __shared__ float Ks[5][QLD];
  __shared__ float Vs[5][QLD];
  __shared__ float P[H_][5][5];
  int tid = threadIdx.x;
  const float scale = 0.08838834764831845f;  // 128^-0.5
  int rows[5];
  rows[0] = s;
#pragma unroll
  for (int i = 1; i < 5; ++i) rows[i] = R_ + 4 * s + (i - 1);
  for (int idx = tid; idx < 5 * D_; idx += 256) {
    int i = idx >> 9, c = idx & (D_ - 1);
    size_t base = (size_t)b * TOT_ + rows[i];
    Qs[i][c] = bf2f(Q[base * D_ + c]) * scale;
    Ks[i][c] = bf2f(KV[base * (2 * D_) + c]);
    Vs[i][c] = bf2f(KV[base * (2 * D_) + D_ + c]);
  }
  __syncthreads();
  int h = tid >> 6, lane = tid & 63;
  if (lane < 25) {
    int i = lane / 5, j = lane % 5;
    float sum = 0.f;
    const float* qp = &Qs[i][h * DH_];
    const float* kp = &Ks[j][h * DH_];
#pragma unroll 8
    for (int d = 0; d < DH_; ++d) sum += qp[d] * kp[d];
    P[h][i][j] = sum;
  }
  __syncthreads();
  if (lane < 5) {
    int i = lane;
    float m = P[h][i][0];
#pragma unroll
    for (int j = 1; j < 5; ++j) m = fmaxf(m, P[h][i][j]);
    float e[5], ssum = 0.f;
#pragma unroll
    for (int j = 0; j < 5; ++j) { e[j] = __expf(P[h][i][j] - m); ssum += e[j]; }
    float inv = 1.0f / ssum;
#pragma unroll
    for (int j = 0; j < 5; ++j) P[h][i][j] = e[j] * inv;
  }
  __syncthreads();
  for (int idx = lane; idx < 5 * DH_; idx += 64) {
    int i = idx >> 7, d = idx & (DH_ - 1);
    float o = 0.f;
#pragma unroll
    for (int j = 0; j < 5; ++j) o += P[h][i][j] * Vs[j][h * DH_ + d];
    O[((size_t)b * TOT_ + rows[i]) * D_ + h * DH_ + d] = f2bf(o);
  }
}

// ---------------------------------------------------------------------------
// mean over the 1024 u rows -> (B, D), two stages.
// ---------------------------------------------------------------------------
__global__ __launch_bounds__(256)
void mean_part_k(const float* __restrict__ X, float* __restrict__ part) {
  int d = blockIdx.x * 256 + threadIdx.x;       // 0..511
  int jc = blockIdx.y;                          // 0..7
  int b = blockIdx.z;                           // 0..7
  float acc = 0.f;
  const float* base = X + ((size_t)b * TOT_ + R_ + jc * 128) * D_ + d;
  for (int j = 0; j < 128; ++j) acc += base[(size_t)j * D_];
  part[((size_t)b * 8 + jc) * D_ + d] = acc;
}

__global__ __launch_bounds__(256)
void mean_final_k(const float* __restrict__ part, float* __restrict__ out) {
  int i = blockIdx.x * 256 + threadIdx.x;       // 0..4095
  int b = i >> 9, d = i & (D_ - 1);
  float acc = 0.f;
#pragma unroll
  for (int c = 0; c < 8; ++c) acc += part[((size_t)b * 8 + c) * D_ + d];
  out[i] = acc * (1.0f / U_);
}

// ---------------------------------------------------------------------------
// Launch. Workspace layout (byte offsets):
//   X    @ 0         fp32  20,971,520
//   LN   @ 20971520  bf16  10,485,760   (alias ATT)
//   Qb   @ 31457280  bf16  10,485,760   (alias LN2)
//   KVb  @ 41943040  bf16  20,971,520   (alias Hb)
//   part @ 62914560  fp32     131,072
//   Wbf  @ 63045632  bf16   9,437,184   (Wq,Wkv,Wo,W1,W2)
// total ~72.5 MB
// ---------------------------------------------------------------------------
extern "C" void kernel_launch(void* const* d_in, const int* in_sizes, int n_in,
                              void* d_out, int out_size, void* d_ws, size_t ws_size,
                              hipStream_t stream) {
  const float* x      = (const float*)d_in[0];
  const float* Wq     = (const float*)d_in[1];
  const float* bq     = (const float*)d_in[2];
  const float* Wkv    = (const float*)d_in[3];
  const float* bkv    = (const float*)d_in[4];
  const float* Wo     = (const float*)d_in[5];
  const float* bo     = (const float*)d_in[6];
  const float* W1     = (const float*)d_in[7];
  const float* b1     = (const float*)d_in[8];
  const float* W2     = (const float*)d_in[9];
  const float* b2     = (const float*)d_in[10];
  const float* ln_in_g  = (const float*)d_in[11];
  const float* ln_in_b  = (const float*)d_in[12];
  const float* ff_ln_g  = (const float*)d_in[13];
  const float* ff_ln_b  = (const float*)d_in[14];
  const float* ln_out_g = (const float*)d_in[15];
  const float* ln_out_b = (const float*)d_in[16];
  float* out = (float*)d_out;

  char* wsb = (char*)d_ws;
  float* X    = (float*)wsb;
  u16*   LN   = (u16*)(wsb + 20971520);
  u16*   Qb   = (u16*)(wsb + 31457280);
  u16*   KVb  = (u16*)(wsb + 41943040);
  float* part = (float*)(wsb + 62914560);
  u16*   Wqb  = (u16*)(wsb + 63045632);
  u16*   Wkvb = Wqb  + 4 * 512 * 512;
  u16*   Wob  = Wkvb + 4 * 1024 * 512;
  u16*   W1b  = Wob  + 4 * 512 * 512;
  u16*   W2b  = W1b  + 4 * 128 * 512;
  u16* ATT = LN;
  u16* LN2 = Qb;
  u16* Hb  = KVb;

  // weights fp32 -> bf16 (once per call)
  cvt_k<<<(4 * 512 * 512) / 1024, 256, 0, stream>>>(Wq,  Wqb,  4 * 512 * 512);
  cvt_k<<<(4 * 1024 * 512) / 1024, 256, 0, stream>>>(Wkv, Wkvb, 4 * 1024 * 512);
  cvt_k<<<(4 * 512 * 512) / 1024, 256, 0, stream>>>(Wo,  Wob,  4 * 512 * 512);
  cvt_k<<<(4 * 128 * 512) / 1024, 256, 0, stream>>>(W1,  W1b,  4 * 128 * 512);
  cvt_k<<<(4 * 128 * 512) / 1024, 256, 0, stream>>>(W2,  W2b,  4 * 128 * 512);

  // build cat
  gather_k<<<(M_ * D_) / 256, 256, 0, stream>>>(x, X);

  for (int l = 0; l < L_; ++l) {
    const u16* Wq_l  = Wqb  + (size_t)l * D_ * D_;
    const u16* Wkv_l = Wkvb + (size_t)l * 2 * D_ * D_;
    const u16* Wo_l  = Wob  + (size_t)l * D_ * D_;
    const u16* W1_l  = W1b  + (size_t)l * FFN_ * D_;
    const u16* W2_l  = W2b  + (size_t)l * D_ * FFN_;
    const float* bq_l  = bq  + (size_t)l * D_;
    const float* bkv_l = bkv + (size_t)l * 2 * D_;
    const float* bo_l  = bo  + (size_t)l * D_;
    const float* b1_l  = b1  + (size_t)l * FFN_;
    const float* b2_l  = b2  + (size_t)l * D_;

    // LN-in: X -> LN (bf16)
    ln_k<true><<<M_, 256, 0, stream>>>(X, ln_in_g + l * D_, ln_in_b + l * D_, LN);

    // Q = LN @ Wq^T + bq  (bf16 out)
    gemm_mfma<false, false, true><<<dim3(D_ / GBN, M_ / GBM), 256, 0, stream>>>(
        LN, Wq_l, bq_l, nullptr, Qb, M_, D_, D_);
    // KV = LN @ Wkv^T + bkv  (bf16 out)
    gemm_mfma<false, false, true><<<dim3(2 * D_ / GBN, M_ / GBM), 256, 0, stream>>>(
        LN, Wkv_l, bkv_l, nullptr, KVb, M_, 2 * D_, D_);

    // attention -> ATT (bf16, reuses LN region)
    attn_k<<<B_ * NSEG_, 256, 0, stream>>>(Qb, KVb, ATT);

    // X = ATT @ Wo^T + bo + X  (fp32 out)
    gemm_mfma<false, true, false><<<dim3(D_ / GBN, M_ / GBM), 256, 0, stream>>>(
        ATT, Wo_l, bo_l, X, X, M_, D_, D_);

    // LN-ff: X -> LN2 (bf16)
    ln_k<true><<<M_, 256, 0, stream>>>(X, ff_ln_g + l * D_, ff_ln_b + l * D_, LN2);

    // H = relu(LN2 @ W1^T + b1)  (bf16 out)
    gemm_mfma<true, false, true><<<dim3(FFN_ / GBN, M_ / GBM), 256, 0, stream>>>(
        LN2, W1_l, b1_l, nullptr, Hb, M_, FFN_, D_);

    // X = H @ W2^T + b2 + X  (fp32 out)
    gemm_mfma<false, true, false><<<dim3(D_ / GBN, M_ / GBM), 256, 0, stream>>>(
        Hb, W2_l, b2_l, X, X, M_, D_, FFN_);

    // LN-out in place (fp32)
    ln_k<false><<<M_, 256, 0, stream>>>(X, ln_out_g + l * D_, ln_out_b + l * D_, X);
  }

  // output mean over u rows
  mean_part_k<<<dim3(2, 8, 8), 256, 0, stream>>>(X, part);
  mean_final_k<<<(B_ * D_) / 256, 256, 0, stream>>>(part, out);
}

// Round 3
// 437.711 us; speedup vs baseline: 4.1427x; 1.3291x over previous
//
#include <hip/hip_runtime.h>
#include <cstdint>
#include <cstddef>

// Problem constants
#define D_    512
#define H_    4
#define DH_   128
#define FFN_  128
#define L_    4
#define B_    8
#define T_    1025
#define U_    1024
#define NSEG_ 256
#define R_    256
#define TOT_  1280            // R + U
#define M_    (B_*TOT_)       // 10240 rows
#define CH_   1536            // QKV channels

typedef __attribute__((ext_vector_type(8))) short bf16x8;
typedef __attribute__((ext_vector_type(4))) float f32x4;
typedef unsigned short u16;

__device__ __forceinline__ u16 f2bf(float f) {
  unsigned u = __builtin_bit_cast(unsigned, f);
  u += 0x7fff + ((u >> 16) & 1);           // round-to-nearest-even
  return (u16)(u >> 16);
}
__device__ __forceinline__ float bf2f(u16 h) {
  unsigned u = ((unsigned)h) << 16;
  return __builtin_bit_cast(float, u);
}

__device__ __forceinline__ void gload_lds16(const void* g, void* l) {
  __builtin_amdgcn_global_load_lds(
      (const __attribute__((address_space(1))) unsigned*)g,
      (__attribute__((address_space(3))) unsigned*)l, 16, 0, 0);
}

// ---------------------------------------------------------------------------
// one-shot weight conversion / packing:
//   WQKVb[l][1536][512] bf16  (rows 0-511 = Wq[l], 512-1535 = Wkv[l])
//   Wob, W1b, W2b bf16 straight copies
//   bQKV[l][1536] fp32        (bq | bkv)
// ---------------------------------------------------------------------------
__global__ __launch_bounds__(256)
void cvt_all_k(const float* __restrict__ Wq, const float* __restrict__ Wkv,
               const float* __restrict__ Wo, const float* __restrict__ W1,
               const float* __restrict__ W2, const float* __restrict__ bq,
               const float* __restrict__ bkv,
               u16* __restrict__ WQKVb, u16* __restrict__ Wob,
               u16* __restrict__ W1b, u16* __restrict__ W2b,
               float* __restrict__ bQKV) {
  int i4 = blockIdx.x * 256 + threadIdx.x;
  if (i4 < 786432) {                        // WQKV: 3,145,728 elems
    int e = i4 * 4;
    int l = e / 786432;
    int rem = e - l * 786432;
    int n = rem >> 9, k = rem & 511;
    const float* src = (n < 512) ? (Wq + (size_t)l * 262144 + n * 512 + k)
                                 : (Wkv + (size_t)l * 524288 + (n - 512) * 512 + k);
    float4 v = *(const float4*)src;
    ushort4 o; o.x = f2bf(v.x); o.y = f2bf(v.y); o.z = f2bf(v.z); o.w = f2bf(v.w);
    *(ushort4*)(WQKVb + e) = o;
  } else if (i4 < 1048576) {                // Wo: 1,048,576 elems
    int e = (i4 - 786432) * 4;
    float4 v = *(const float4*)(Wo + e);
    ushort4 o; o.x = f2bf(v.x); o.y = f2bf(v.y); o.z = f2bf(v.z); o.w = f2bf(v.w);
    *(ushort4*)(Wob + e) = o;
  } else if (i4 < 1114112) {                // W1: 262,144
    int e = (i4 - 1048576) * 4;
    float4 v = *(const float4*)(W1 + e);
    ushort4 o; o.x = f2bf(v.x); o.y = f2bf(v.y); o.z = f2bf(v.z); o.w = f2bf(v.w);
    *(ushort4*)(W1b + e) = o;
  } else if (i4 < 1179648) {                // W2: 262,144
    int e = (i4 - 1114112) * 4;
    float4 v = *(const float4*)(W2 + e);
    ushort4 o; o.x = f2bf(v.x); o.y = f2bf(v.y); o.z = f2bf(v.z); o.w = f2bf(v.w);
    *(ushort4*)(W2b + e) = o;
  } else if (i4 < 1181184) {                // bias: 6144 elems
    int e = (i4 - 1179648) * 4;
    int l = e / 1536, n = e - l * 1536;
#pragma unroll
    for (int t = 0; t < 4; ++t) {
      int nn = n + t;
      bQKV[e + t] = (nn < 512) ? bq[l * 512 + nn] : bkv[l * 1024 + (nn - 512)];
    }
  }
}

// ---------------------------------------------------------------------------
// gather + LN-in(layer 0): builds X (fp32 residual) and LNbuf (bf16)
// ---------------------------------------------------------------------------
__global__ __launch_bounds__(256)
void gather_ln_k(const float* __restrict__ x, const float* __restrict__ g,
                 const float* __restrict__ bb, float* __restrict__ X,
                 u16* __restrict__ LNb) {
  int row = blockIdx.x;
  int tid = threadIdx.x;
  int b = row / TOT_, p = row % TOT_;
  int t = (p < R_) ? ((p < R_ - 1) ? 4 * (p + 1) : (T_ - 1)) : (p - R_);
  const float* xr = x + ((size_t)b * T_ + t) * D_;
  float e0 = xr[tid], e1 = xr[tid + 256];
  X[(size_t)row * D_ + tid] = e0;
  X[(size_t)row * D_ + tid + 256] = e1;
  float s = e0 + e1, ss = e0 * e0 + e1 * e1;
#pragma unroll
  for (int off = 32; off > 0; off >>= 1) {
    s  += __shfl_down(s, off);
    ss += __shfl_down(ss, off);
  }
  __shared__ float red[10];
  int wid = tid >> 6, lane = tid & 63;
  if (lane == 0) { red[wid] = s; red[4 + wid] = ss; }
  __syncthreads();
  if (tid == 0) {
    float S = red[0] + red[1] + red[2] + red[3];
    float SS = red[4] + red[5] + red[6] + red[7];
    float mu = S * (1.0f / D_);
    float var = SS * (1.0f / D_) - mu * mu;
    if (var < 0.f) var = 0.f;
    red[8] = mu; red[9] = rsqrtf(var + 1e-5f);
  }
  __syncthreads();
  float mu = red[8], rs = red[9];
  u16* yr = LNb + (size_t)row * D_;
  yr[tid]       = f2bf((e0 - mu) * rs * g[tid]       + bb[tid]);
  yr[tid + 256] = f2bf((e1 - mu) * rs * g[tid + 256] + bb[tid + 256]);
}

// ---------------------------------------------------------------------------
// bf16 MFMA GEMM (128x128 tile, BK=32, 4 waves): C = A @ B^T + bias, bf16 out.
// Used for the fused QKV projection (N=1536).
// ---------------------------------------------------------------------------
#define GBM 128
#define GBN 128
#define GBK 32

__global__ __launch_bounds__(256)
void gemm_qkv(const u16* __restrict__ A, const u16* __restrict__ Bw,
              const float* __restrict__ bias, u16* __restrict__ Cout,
              int M, int N, int K) {
  __shared__ __align__(16) u16 As[GBM * GBK];
  __shared__ __align__(16) u16 Bs[GBN * GBK];
  const int tid = threadIdx.x;
  const int wid = tid >> 6;
  const int lane = tid & 63;
  const int bm = blockIdx.y * GBM;
  const int bn = blockIdx.x * GBN;
  const int wr = wid >> 1, wc = wid & 1;

  const int srow = tid >> 2;
  const int skoff = (tid & 3) << 3;

  f32x4 acc[4][4] = {};

  const u16* Ag0 = A  + (size_t)(bm + srow)      * K + skoff;
  const u16* Ag1 = A  + (size_t)(bm + 64 + srow) * K + skoff;
  const u16* Bg0 = Bw + (size_t)(bn + srow)      * K + skoff;
  const u16* Bg1 = Bw + (size_t)(bn + 64 + srow) * K + skoff;
  u16* AsW0 = &As[(size_t)(wid * 16)      * GBK];
  u16* AsW1 = &As[(size_t)(64 + wid * 16) * GBK];
  u16* BsW0 = &Bs[(size_t)(wid * 16)      * GBK];
  u16* BsW1 = &Bs[(size_t)(64 + wid * 16) * GBK];

  const int lrow = lane & 15;
  const int lko  = (lane >> 4) * 16;

  for (int k0 = 0; k0 < K; k0 += GBK) {
    __syncthreads();
    gload_lds16(Ag0 + k0, AsW0);
    gload_lds16(Ag1 + k0, AsW1);
    gload_lds16(Bg0 + k0, BsW0);
    gload_lds16(Bg1 + k0, BsW1);
    __syncthreads();

    bf16x8 afrag[4], bfrag[4];
#pragma unroll
    for (int m = 0; m < 4; ++m) {
      int row = wr * 64 + m * 16 + lrow;
      afrag[m] = *(const bf16x8*)((const char*)As + row * (GBK * 2) + lko);
    }
#pragma unroll
    for (int n = 0; n < 4; ++n) {
      int col = wc * 64 + n * 16 + lrow;
      bfrag[n] = *(const bf16x8*)((const char*)Bs + col * (GBK * 2) + lko);
    }
#pragma unroll
    for (int m = 0; m < 4; ++m)
#pragma unroll
      for (int n = 0; n < 4; ++n)
        acc[m][n] = __builtin_amdgcn_mfma_f32_16x16x32_bf16(
            afrag[m], bfrag[n], acc[m][n], 0, 0, 0);
  }

  const int lcol  = lane & 15;
  const int lrow4 = (lane >> 4) * 4;
#pragma unroll
  for (int m = 0; m < 4; ++m) {
    int rowbase = bm + wr * 64 + m * 16 + lrow4;
#pragma unroll
    for (int n = 0; n < 4; ++n) {
      int col = bn + wc * 64 + n * 16 + lcol;
      float bv = bias[col];
#pragma unroll
      for (int j = 0; j < 4; ++j) {
        int row = rowbase + j;
        ((u16*)Cout)[(size_t)row * N + col] = f2bf(acc[m][n][j] + bv);
      }
    }
  }
}

// ---------------------------------------------------------------------------
// full-row GEMM + fused LayerNorm epilogue. Tile 32 rows x 512 cols, 4 waves
// (wave w owns cols [w*128, w*128+128)), BK=32. Always residual-add.
// MODE 0 (O-proj): write pre-LN to Xout fp32; LN(g1,b1) -> OutBf bf16.
// MODE 1 (FFN2, l<3): LN1(g1,b1) -> Xout fp32; LN2(g2,b2) -> OutBf bf16.
// MODE 2 (FFN2, l=3): LN1(g1,b1) -> Xout fp32 only.
// ---------------------------------------------------------------------------
template <int MODE>
__global__ __launch_bounds__(256)
void gemm_row_ln(const u16* __restrict__ A, const u16* __restrict__ Bw,
                 const float* __restrict__ bias, const float* __restrict__ Rsd,
                 float* __restrict__ Xout,
                 const float* __restrict__ g1, const float* __restrict__ b1,
                 const float* __restrict__ g2, const float* __restrict__ b2,
                 u16* __restrict__ OutBf, int K) {
  __shared__ __align__(16) u16 As[32 * 32];
  __shared__ __align__(16) u16 Bs[512 * 32];
  __shared__ float wsum[4][32], wss[4][32], mu_s[32], rs_s[32];
  const int tid = threadIdx.x;
  const int wid = tid >> 6, lane = tid & 63;
  const int bm = blockIdx.x * 32;
  const int l4 = lane >> 2;          // 0..15: row within a 16-row gload
  const int k8 = (lane & 3) << 3;    // k element offset
  const int lrow = lane & 15;
  const int lko  = (lane >> 4) * 16; // byte offset within 64B row

  f32x4 acc[2][8] = {};

  const u16* Ag = A + (size_t)(bm + (wid & 1) * 16 + l4) * K + k8;

  for (int k0 = 0; k0 < K; k0 += 32) {
    __syncthreads();
    if (wid < 2)
      gload_lds16(Ag + k0, (char*)As + (wid * 16) * 64);
#pragma unroll
    for (int p = 0; p < 8; ++p) {
      int row = wid * 128 + p * 16 + l4;
      gload_lds16(Bw + (size_t)row * K + k0 + k8,
                  (char*)Bs + (wid * 128 + p * 16) * 64);
    }
    __syncthreads();

    bf16x8 af[2], bf[8];
#pragma unroll
    for (int m = 0; m < 2; ++m)
      af[m] = *(const bf16x8*)((const char*)As + (m * 16 + lrow) * 64 + lko);
#pragma unroll
    for (int n = 0; n < 8; ++n)
      bf[n] = *(const bf16x8*)((const char*)Bs + (wid * 128 + n * 16 + lrow) * 64 + lko);
#pragma unroll
    for (int m = 0; m < 2; ++m)
#pragma unroll
      for (int n = 0; n < 8; ++n)
        acc[m][n] = __builtin_amdgcn_mfma_f32_16x16x32_bf16(
            af[m], bf[n], acc[m][n], 0, 0, 0);
  }

  // ---- epilogue: bias + residual ----
  const int lcol = lane & 15;
  const int lr4 = (lane >> 4) * 4;
#pragma unroll
  for (int n = 0; n < 8; ++n) {
    int col = wid * 128 + n * 16 + lcol;
    float bv = bias[col];
#pragma unroll
    for (int m = 0; m < 2; ++m)
#pragma unroll
      for (int j = 0; j < 4; ++j) {
        int row = bm + m * 16 + lr4 + j;
        float t = acc[m][n][j] + bv + Rsd[(size_t)row * D_ + col];
        if (MODE == 0) Xout[(size_t)row * D_ + col] = t;
        acc[m][n][j] = t;
      }
  }

  // ---- LN pass 1: stats over 512 cols per row ----
  {
    float s0[2][4] = {}, s1[2][4] = {};
#pragma unroll
    for (int m = 0; m < 2; ++m)
#pragma unroll
      for (int n = 0; n < 8; ++n)
#pragma unroll
        for (int j = 0; j < 4; ++j) {
          float v = acc[m][n][j];
          s0[m][j] += v; s1[m][j] += v * v;
        }
#pragma unroll
    for (int off = 1; off < 16; off <<= 1)
#pragma unroll
      for (int m = 0; m < 2; ++m)
#pragma unroll
        for (int j = 0; j < 4; ++j) {
          s0[m][j] += __shfl_xor(s0[m][j], off);
          s1[m][j] += __shfl_xor(s1[m][j], off);
        }
    if ((lane & 15) == 0) {
#pragma unroll
      for (int m = 0; m < 2; ++m)
#pragma unroll
        for (int j = 0; j < 4; ++j) {
          int r = m * 16 + lr4 + j;
          wsum[wid][r] = s0[m][j]; wss[wid][r] = s1[m][j];
        }
    }
  }
  __syncthreads();
  if (tid < 32) {
    float S  = wsum[0][tid] + wsum[1][tid] + wsum[2][tid] + wsum[3][tid];
    float SS = wss[0][tid] + wss[1][tid] + wss[2][tid] + wss[3][tid];
    float mu = S * (1.0f / D_);
    float var = SS * (1.0f / D_) - mu * mu;
    if (var < 0.f) var = 0.f;
    mu_s[tid] = mu; rs_s[tid] = rsqrtf(var + 1e-5f);
  }
  __syncthreads();

  float gg[8], bv2[8];
#pragma unroll
  for (int n = 0; n < 8; ++n) {
    int col = wid * 128 + n * 16 + lcol;
    gg[n] = g1[col]; bv2[n] = b1[col];
  }
#pragma unroll
  for (int m = 0; m < 2; ++m)
#pragma unroll
    for (int n = 0; n < 8; ++n) {
      int col = wid * 128 + n * 16 + lcol;
#pragma unroll
      for (int j = 0; j < 4; ++j) {
        int r = m * 16 + lr4 + j;
        int row = bm + r;
        float ln = (acc[m][n][j] - mu_s[r]) * rs_s[r] * gg[n] + bv2[n];
        if (MODE == 0) {
          OutBf[(size_t)row * D_ + col] = f2bf(ln);
        } else {
          Xout[(size_t)row * D_ + col] = ln;
          acc[m][n][j] = ln;
        }
      }
    }

  if (MODE == 1) {
    // ---- LN pass 2 on LN1 output ----
    __syncthreads();   // wsum/wss safe to reuse
    {
      float s0[2][4] = {}, s1[2][4] = {};
#pragma unroll
      for (int m = 0; m < 2; ++m)
#pragma unroll
        for (int n = 0; n < 8; ++n)
#pragma unroll
          for (int j = 0; j < 4; ++j) {
            float v = acc[m][n][j];
            s0[m][j] += v; s1[m][j] += v * v;
          }
#pragma unroll
      for (int off = 1; off < 16; off <<= 1)
#pragma unroll
        for (int m = 0; m < 2; ++m)
#pragma unroll
          for (int j = 0; j < 4; ++j) {
            s0[m][j] += __shfl_xor(s0[m][j], off);
            s1[m][j] += __shfl_xor(s1[m][j], off);
          }
      if ((lane & 15) == 0) {
#pragma unroll
        for (int m = 0; m < 2; ++m)
#pragma unroll
          for (int j = 0; j < 4; ++j) {
            int r = m * 16 + lr4 + j;
            wsum[wid][r] = s0[m][j]; wss[wid][r] = s1[m][j];
          }
      }
    }
    __syncthreads();
    if (tid < 32) {
      float S  = wsum[0][tid] + wsum[1][tid] + wsum[2][tid] + wsum[3][tid];
      float SS = wss[0][tid] + wss[1][tid] + wss[2][tid] + wss[3][tid];
      float mu = S * (1.0f / D_);
      float var = SS * (1.0f / D_) - mu * mu;
      if (var < 0.f) var = 0.f;
      mu_s[tid] = mu; rs_s[tid] = rsqrtf(var + 1e-5f);
    }
    __syncthreads();
#pragma unroll
    for (int n = 0; n < 8; ++n) {
      int col = wid * 128 + n * 16 + lcol;
      gg[n] = g2[col]; bv2[n] = b2[col];
    }
#pragma unroll
    for (int m = 0; m < 2; ++m)
#pragma unroll
      for (int n = 0; n < 8; ++n) {
        int col = wid * 128 + n * 16 + lcol;
#pragma unroll
        for (int j = 0; j < 4; ++j) {
          int r = m * 16 + lr4 + j;
          int row = bm + r;
          float ln = (acc[m][n][j] - mu_s[r]) * rs_s[r] * gg[n] + bv2[n];
          OutBf[(size_t)row * D_ + col] = f2bf(ln);
        }
      }
  }
}

// ---------------------------------------------------------------------------
// FFN1: H = relu(A @ W1^T + b1), tile 32 rows x 128 cols, wave w owns
// cols [w*32, w*32+32). K=512.
// ---------------------------------------------------------------------------
__global__ __launch_bounds__(256)
void gemm_ffn1(const u16* __restrict__ A, const u16* __restrict__ Bw,
               const float* __restrict__ bias, u16* __restrict__ Hout) {
  __shared__ __align__(16) u16 As[32 * 32];
  __shared__ __align__(16) u16 Bs[128 * 32];
  const int tid = threadIdx.x;
  const int wid = tid >> 6, lane = tid & 63;
  const int bm = blockIdx.x * 32;
  const int l4 = lane >> 2;
  const int k8 = (lane & 3) << 3;
  const int lrow = lane & 15;
  const int lko  = (lane >> 4) * 16;

  f32x4 acc[2][2] = {};
  const u16* Ag = A + (size_t)(bm + (wid & 1) * 16 + l4) * D_ + k8;

  for (int k0 = 0; k0 < D_; k0 += 32) {
    __syncthreads();
    if (wid < 2)
      gload_lds16(Ag + k0, (char*)As + (wid * 16) * 64);
#pragma unroll
    for (int p = 0; p < 2; ++p) {
      int row = wid * 32 + p * 16 + l4;
      gload_lds16(Bw + (size_t)row * D_ + k0 + k8,
                  (char*)Bs + (wid * 32 + p * 16) * 64);
    }
    __syncthreads();
    bf16x8 af[2], bf[2];
#pragma unroll
    for (int m = 0; m < 2; ++m)
      af[m] = *(const bf16x8*)((const char*)As + (m * 16 + lrow) * 64 + lko);
#pragma unroll
    for (int n = 0; n < 2; ++n)
      bf[n] = *(const bf16x8*)((const char*)Bs + (wid * 32 + n * 16 + lrow) * 64 + lko);
#pragma unroll
    for (int m = 0; m < 2; ++m)
#pragma unroll
      for (int n = 0; n < 2; ++n)
        acc[m][n] = __builtin_amdgcn_mfma_f32_16x16x32_bf16(
            af[m], bf[n], acc[m][n], 0, 0, 0);
  }

  const int lcol = lane & 15;
  const int lr4 = (lane >> 4) * 4;
#pragma unroll
  for (int m = 0; m < 2; ++m)
#pragma unroll
    for (int n = 0; n < 2; ++n) {
      int col = wid * 32 + n * 16 + lcol;
      float bv = bias[col];
#pragma unroll
      for (int j = 0; j < 4; ++j) {
        int row = bm + m * 16 + lr4 + j;
        float v = fmaxf(acc[m][n][j] + bv, 0.f);
        Hout[(size_t)row * FFN_ + col] = f2bf(v);
      }
    }
}

// ---------------------------------------------------------------------------
// Block-diagonal attention reading fused QKV (stride 1536).
// One block per (b, seg); wave h = head h. Segment rows: {s, 256+4s..+3}.
// ---------------------------------------------------------------------------
#define QLD 516
__global__ __launch_bounds__(256)
void attn_k(const u16* __restrict__ QKV, u16* __restrict__ O) {
  int bs = blockIdx.x;
  int b = bs >> 8, s = bs & 255;
  __shared__ float Qs[5][QLD];
  __shared__ float Ks[5][QLD];
  __shared__ float Vs[5][QLD];
  __shared__ float P[H_][5][5];
  int tid = threadIdx.x;
  const float scale = 0.08838834764831845f;
  int rows[5];
  rows[0] = s;
#pragma unroll
  for (int i = 1; i < 5; ++i) rows[i] = R_ + 4 * s + (i - 1);
  for (int idx = tid; idx < 5 * D_; idx += 256) {
    int i = idx >> 9, c = idx & (D_ - 1);
    size_t base = ((size_t)b * TOT_ + rows[i]) * CH_;
    Qs[i][c] = bf2f(QKV[base + c]) * scale;
    Ks[i][c] = bf2f(QKV[base + D_ + c]);
    Vs[i][c] = bf2f(QKV[base + 2 * D_ + c]);
  }
  __syncthreads();
  int h = tid >> 6, lane = tid & 63;
  if (lane < 25) {
    int i = lane / 5, j = lane % 5;
    float sum = 0.f;
    const float* qp = &Qs[i][h * DH_];
    const float* kp = &Ks[j][h * DH_];
#pragma unroll 8
    for (int d = 0; d < DH_; ++d) sum += qp[d] * kp[d];
    P[h][i][j] = sum;
  }
  __syncthreads();
  if (lane < 5) {
    int i = lane;
    float m = P[h][i][0];
#pragma unroll
    for (int j = 1; j < 5; ++j) m = fmaxf(m, P[h][i][j]);
    float e[5], ssum = 0.f;
#pragma unroll
    for (int j = 0; j < 5; ++j) { e[j] = __expf(P[h][i][j] - m); ssum += e[j]; }
    float inv = 1.0f / ssum;
#pragma unroll
    for (int j = 0; j < 5; ++j) P[h][i][j] = e[j] * inv;
  }
  __syncthreads();
  for (int idx = lane; idx < 5 * DH_; idx += 64) {
    int i = idx >> 7, d = idx & (DH_ - 1);
    float o = 0.f;
#pragma unroll
    for (int j = 0; j < 5; ++j) o += P[h][i][j] * Vs[j][h * DH_ + d];
    O[((size_t)b * TOT_ + rows[i]) * D_ + h * DH_ + d] = f2bf(o);
  }
}

// ---------------------------------------------------------------------------
// mean over the 1024 u rows -> (B, D), two stages.
// ---------------------------------------------------------------------------
__global__ __launch_bounds__(256)
void mean_part_k(const float* __restrict__ X, float* __restrict__ part) {
  int d = blockIdx.x * 256 + threadIdx.x;
  int jc = blockIdx.y;
  int b = blockIdx.z;
  float acc = 0.f;
  const float* base = X + ((size_t)b * TOT_ + R_ + jc * 128) * D_ + d;
  for (int j = 0; j < 128; ++j) acc += base[(size_t)j * D_];
  part[((size_t)b * 8 + jc) * D_ + d] = acc;
}

__global__ __launch_bounds__(256)
void mean_final_k(const float* __restrict__ part, float* __restrict__ out) {
  int i = blockIdx.x * 256 + threadIdx.x;
  int b = i >> 9, d = i & (D_ - 1);
  float acc = 0.f;
#pragma unroll
  for (int c = 0; c < 8; ++c) acc += part[((size_t)b * 8 + c) * D_ + d];
  out[i] = acc * (1.0f / U_);
}

// ---------------------------------------------------------------------------
// Launch. Workspace layout (byte offsets):
//   X      @ 0          fp32 20,971,520
//   LNbuf  @ 20971520   bf16 10,485,760
//   QKV    @ 31457280   bf16 31,457,280
//   ATT    @ 62914560   bf16 10,485,760
//   LN2buf @ 73400320   bf16 10,485,760
//   H      @ 83886080   bf16  2,621,440
//   part   @ 86507520   fp32    131,072
//   WQKVb  @ 86638592   bf16  6,291,456
//   Wob    @ 92930048   bf16  2,097,152
//   W1b    @ 95027200   bf16    524,288
//   W2b    @ 95551488   bf16    524,288
//   bQKV   @ 96075776   fp32     24,576
// total ~96.1 MB
// ---------------------------------------------------------------------------
extern "C" void kernel_launch(void* const* d_in, const int* in_sizes, int n_in,
                              void* d_out, int out_size, void* d_ws, size_t ws_size,
                              hipStream_t stream) {
  const float* x      = (const float*)d_in[0];
  const float* Wq     = (const float*)d_in[1];
  const float* bq     = (const float*)d_in[2];
  const float* Wkv    = (const float*)d_in[3];
  const float* bkv    = (const float*)d_in[4];
  const float* Wo     = (const float*)d_in[5];
  const float* bo     = (const float*)d_in[6];
  const float* W1     = (const float*)d_in[7];
  const float* b1     = (const float*)d_in[8];
  const float* W2     = (const float*)d_in[9];
  const float* b2     = (const float*)d_in[10];
  const float* ln_in_g  = (const float*)d_in[11];
  const float* ln_in_b  = (const float*)d_in[12];
  const float* ff_ln_g  = (const float*)d_in[13];
  const float* ff_ln_b  = (const float*)d_in[14];
  const float* ln_out_g = (const float*)d_in[15];
  const float* ln_out_b = (const float*)d_in[16];
  float* out = (float*)d_out;

  char* wsb = (char*)d_ws;
  float* X     = (float*)wsb;
  u16*   LNbuf = (u16*)(wsb + 20971520);
  u16*   QKV   = (u16*)(wsb + 31457280);
  u16*   ATT   = (u16*)(wsb + 62914560);
  u16*   LN2b  = (u16*)(wsb + 73400320);
  u16*   Hb    = (u16*)(wsb + 83886080);
  float* part  = (float*)(wsb + 86507520);
  u16*   WQKVb = (u16*)(wsb + 86638592);
  u16*   Wob   = (u16*)(wsb + 92930048);
  u16*   W1b   = (u16*)(wsb + 95027200);
  u16*   W2b   = (u16*)(wsb + 95551488);
  float* bQKV  = (float*)(wsb + 96075776);

  cvt_all_k<<<4614, 256, 0, stream>>>(Wq, Wkv, Wo, W1, W2, bq, bkv,
                                      WQKVb, Wob, W1b, W2b, bQKV);
  gather_ln_k<<<M_, 256, 0, stream>>>(x, ln_in_g, ln_in_b, X, LNbuf);

  for (int l = 0; l < L_; ++l) {
    const u16* WQKV_l = WQKVb + (size_t)l * CH_ * D_;
    const u16* Wo_l   = Wob   + (size_t)l * D_ * D_;
    const u16* W1_l   = W1b   + (size_t)l * FFN_ * D_;
    const u16* W2_l   = W2b   + (size_t)l * D_ * FFN_;
    const float* bQKV_l = bQKV + (size_t)l * CH_;
    const float* bo_l = bo + (size_t)l * D_;
    const float* b1_l = b1 + (size_t)l * FFN_;
    const float* b2_l = b2 + (size_t)l * D_;

    // QKV = LNbuf @ WQKV^T + bQKV
    gemm_qkv<<<dim3(CH_ / GBN, M_ / GBM), 256, 0, stream>>>(
        LNbuf, WQKV_l, bQKV_l, QKV, M_, CH_, D_);

    // attention -> ATT
    attn_k<<<B_ * NSEG_, 256, 0, stream>>>(QKV, ATT);

    // rc_out = ATT @ Wo^T + bo + X  -> X (fp32), LN2b = LN_ff(rc_out) bf16
    gemm_row_ln<0><<<M_ / 32, 256, 0, stream>>>(
        ATT, Wo_l, bo_l, X, X,
        ff_ln_g + l * D_, ff_ln_b + l * D_, nullptr, nullptr, LN2b, D_);

    // H = relu(LN2b @ W1^T + b1)
    gemm_ffn1<<<M_ / 32, 256, 0, stream>>>(LN2b, W1_l, b1_l, Hb);

    // X = LN_out(H @ W2^T + b2 + X); LNbuf = LN_in[l+1](X) if l<3
    if (l < L_ - 1) {
      gemm_row_ln<1><<<M_ / 32, 256, 0, stream>>>(
          Hb, W2_l, b2_l, X, X,
          ln_out_g + l * D_, ln_out_b + l * D_,
          ln_in_g + (l + 1) * D_, ln_in_b + (l + 1) * D_, LNbuf, FFN_);
    } else {
      gemm_row_ln<2><<<M_ / 32, 256, 0, stream>>>(
          Hb, W2_l, b2_l, X, X,
          ln_out_g + l * D_, ln_out_b + l * D_,
          nullptr, nullptr, nullptr, FFN_);
    }
  }

  mean_part_k<<<dim3(2, 8, 8), 256, 0, stream>>>(X, part);
  mean_final_k<<<(B_ * D_) / 256, 256, 0, stream>>>(part, out);
}